// Round 1
// baseline (173.643 us; speedup 1.0000x reference)
//
#include <hip/hip_runtime.h>

// CompactPiecewiseLinearEmbeddings: out[n,f,:] = C[f][k] + t*(C[f][k+1]-C[f][k])
// where k = #{j in [1,47] : edges[f][j] <= x[n,f]}, t = (x - edges[f][k]) / width[f][k],
// C[f][j] = bias[f] + sum_{b<j} W[f][b][:]   (sorted boundaries => h = [1..1, t, 0..0])
//
// R5: full-residency attack. R4 was still latency-bound: grid=2048 blocks at
// 6 blocks/CU resident (launch_bounds 256,6) => 1536 co-resident + a 33% tail
// generation, 24/32 waves/CU steady state, kernel ~78us vs ~24us HBM roofline.
// LDS is 17.5KB/block so 8 blocks/CU fit (140KB <= 160KB); the blocker was
// VGPRs (2-row ILP needs >64). Change: single row per thread per iteration
// (8 iters, explicit x prefetch kept), __launch_bounds__(256, 8) => all 2048
// blocks resident, 32 waves/CU, zero tail. Latency hiding via TLP not ILP.

#define NN 16384
#define FF 256
#define BB 48
#define DD 8

#define FT 8               // features per block
#define NSPLIT 64          // n-splits
#define NPB (NN / NSPLIT)  // 256 rows per block

#define ESTR 52            // sE stride: 16B-mult, 20f mod 32 all-distinct over f=0..7
#define RASTR 100          // sRA stride (floats): 8B-mult, 4f mod 32 all-distinct
#define CSTR 396           // sC stride: 16B-mult, 12f mod 32 all-distinct

__global__ __launch_bounds__(256, 8)
void cple_kernel(const float* __restrict__ X,
                 const float* __restrict__ Edg,
                 const float* __restrict__ Wid,
                 const float* __restrict__ W,
                 const float* __restrict__ Bias,
                 float* __restrict__ Out)
{
    __shared__ float sE [FT * ESTR];   // edges [f][j=0..47]
    __shared__ float sRA[FT * RASTR];  // [f][j] -> (r_j, -e_j*r_j) pairs
    __shared__ float sC [FT * CSTR];   // cumulative W + bias, [f][j=0..48][d]

    const int tid = threadIdx.x;
    const int f0  = blockIdx.x * FT;
    const int ns  = blockIdx.y;

    // --- stage edges [f][0..47] (96 float4) ---
    if (tid < FT * BB / 4) {
        const float4* E4 = (const float4*)(Edg + (size_t)f0 * BB);
        float4 v = E4[tid];
        int f = tid / 12, j4 = tid % 12;
        *(float4*)&sE[f * ESTR + j4 * 4] = v;
    }
    // --- stage (r, -e*r) pairs ---
    for (int idx = tid; idx < FT * BB; idx += 256) {
        int f = idx / BB, j = idx - f * BB;
        float e = Edg[(size_t)f0 * BB + idx];
        float w = Wid[(size_t)f0 * BB + idx];
        float r = 1.0f / w;
        sRA[f * RASTR + 2 * j]     = r;
        sRA[f * RASTR + 2 * j + 1] = -e * r;
    }
    // --- stage W tile into sC at [f][b+1][d] (768 float4, 3 per thread) ---
    {
        const float4* Wt4 = (const float4*)(W + (size_t)f0 * BB * DD);
        #pragma unroll
        for (int q = 0; q < 3; ++q) {
            int idx4 = tid + q * 256;
            float4 v = Wt4[idx4];
            int idx = idx4 * 4;
            int f   = idx / (BB * DD);
            int rem = idx - f * (BB * DD);
            *(float4*)&sC[f * CSTR + DD + rem] = v;
        }
    }
    __syncthreads();

    // --- coarse search level -> registers (sE ready; overlaps with scan) ---
    const int f_l = tid & 7;
    const int n_l = tid >> 3;                 // 0..31
    const float* eF  = &sE [f_l * ESTR];
    const float* raF = &sRA[f_l * RASTR];
    const float* cF  = &sC [f_l * CSTR];
    float c4[11];
    #pragma unroll
    for (int m = 0; m < 11; ++m) c4[m] = eF[4 * (m + 1)];

    // --- prefix scan: C[f][j][d] = bias + sum_{b<j} W[f][b][d] (reg-chunked) ---
    if (tid < FT * DD) {
        int f = tid >> 3, d = tid & 7;
        float* c = &sC[f * CSTR + d];
        float acc = Bias[(size_t)(f0 + f) * DD + d];
        c[0] = acc;
        #pragma unroll
        for (int ch = 0; ch < 3; ++ch) {
            float w[16];
            #pragma unroll
            for (int j = 0; j < 16; ++j) w[j] = c[(ch * 16 + j + 1) * DD];
            #pragma unroll
            for (int j = 0; j < 16; ++j) { acc += w[j]; c[(ch * 16 + j + 1) * DD] = acc; }
        }
    }
    __syncthreads();

    // --- main loop: 8 features x 32 rows per pass, 1 row/thread/iter, 8 iters ---
    const float* xp = X + (f0 + f_l);
    float* op = Out + (size_t)(f0 + f_l) * DD;

    int n = ns * NPB + n_l;
    float x = xp[(size_t)n * FF];

    #pragma unroll
    for (int i = 0; i < 8; ++i) {
        float xc = x;
        if (i < 7)   // prefetch next row (hides HBM-cold x latency)
            x = xp[(size_t)(n + 32) * FF];

        // coarse: group g = #{m: x >= E[4m+4]}, k4 = 4g (pure VALU, registers)
        int g = 0;
        #pragma unroll
        for (int m = 0; m < 11; ++m) g += (xc >= c4[m]) ? 1 : 0;
        int k4 = g * 4;

        // fine: one aligned b128 of E[k4..k4+3], count 3
        float4 e = *(const float4*)(eF + k4);
        int k = k4 + (xc >= e.y) + (xc >= e.z) + (xc >= e.w);

        // gather round: (r,-e*r) b64 + C[k],C[k+1] 4x b128 (one latency round)
        float2 ra = *(const float2*)(raF + 2 * k);
        const float* cK = cF + k * DD;
        float4 l0 = *(const float4*)(cK);
        float4 l1 = *(const float4*)(cK + 4);
        float4 h0 = *(const float4*)(cK + 8);
        float4 h1 = *(const float4*)(cK + 12);

        float t = fmaf(xc, ra.x, ra.y);

        float4 o0, o1;
        o0.x = fmaf(t, h0.x - l0.x, l0.x);
        o0.y = fmaf(t, h0.y - l0.y, l0.y);
        o0.z = fmaf(t, h0.z - l0.z, l0.z);
        o0.w = fmaf(t, h0.w - l0.w, l0.w);
        o1.x = fmaf(t, h1.x - l1.x, l1.x);
        o1.y = fmaf(t, h1.y - l1.y, l1.y);
        o1.z = fmaf(t, h1.z - l1.z, l1.z);
        o1.w = fmaf(t, h1.w - l1.w, l1.w);

        float4* o = (float4*)(op + (size_t)n * (FF * DD));
        o[0] = o0;
        o[1] = o1;

        n += 32;
    }
}

extern "C" void kernel_launch(void* const* d_in, const int* in_sizes, int n_in,
                              void* d_out, int out_size, void* d_ws, size_t ws_size,
                              hipStream_t stream) {
    const float* x     = (const float*)d_in[0];
    const float* edges = (const float*)d_in[1];
    const float* width = (const float*)d_in[2];
    const float* W     = (const float*)d_in[3];
    const float* b     = (const float*)d_in[4];
    float* out = (float*)d_out;

    dim3 grid(FF / FT, NSPLIT);
    cple_kernel<<<grid, 256, 0, stream>>>(x, edges, width, W, b, out);
}

// Round 2
// 169.137 us; speedup vs baseline: 1.0266x; 1.0266x over previous
//
#include <hip/hip_runtime.h>

// CompactPiecewiseLinearEmbeddings: out[n,f,:] = C[f][k] + t*(C[f][k+1]-C[f][k])
// where k = #{j in [1,47] : edges[f][j] <= x[n,f]}, t = (x - edges[f][k]) / width[f][k],
// C[f][j] = bias[f] + sum_{b<j} W[f][b][:]   (sorted boundaries => h = [1..1, t, 0..0])
//
// R6: exact-fit grid. R5 (1-row TLP @ 8/CU) regressed: the 64-VGPR cap killed
// cross-iteration pipelining. Revert to R4's proven 2-row-ILP body at
// __launch_bounds__(256,6) (~80 VGPR budget) and instead eliminate the tail
// generation: grid 2048 -> 1536 blocks (= 6/CU x 256 CU, all co-resident).
// Each block loops passes p = ns + 48*i (64 rows/pass, 5-6 passes), so the
// machine stays at full occupancy except one 1/3-occupancy slot (~11% waste
// vs R4's 33% second-generation tail). Table staging amortizes over 5.33
// passes instead of 4. First pass's x loads issued BEFORE the first barrier
// so cold-HBM latency hides under staging + prefix scan.

#define NN 16384
#define FF 256
#define BB 48
#define DD 8

#define FT 8               // features per block
#define NSPLIT 48          // n-splits: 32 x 48 = 1536 blocks = exactly 6/CU
#define NPASS (NN / 64)    // 256 passes of 64 rows per feature-column

#define ESTR 52            // sE stride: 16B-mult, 20f mod 32 all-distinct over f=0..7
#define RASTR 100          // sRA stride (floats): 8B-mult, 4f mod 32 all-distinct
#define CSTR 396           // sC stride: 16B-mult, 12f mod 32 all-distinct

__global__ __launch_bounds__(256, 6)
void cple_kernel(const float* __restrict__ X,
                 const float* __restrict__ Edg,
                 const float* __restrict__ Wid,
                 const float* __restrict__ W,
                 const float* __restrict__ Bias,
                 float* __restrict__ Out)
{
    __shared__ float sE [FT * ESTR];   // edges [f][j=0..47]
    __shared__ float sRA[FT * RASTR];  // [f][j] -> (r_j, -e_j*r_j) pairs
    __shared__ float sC [FT * CSTR];   // cumulative W + bias, [f][j=0..48][d]

    const int tid = threadIdx.x;
    const int f0  = blockIdx.x * FT;
    const int ns  = blockIdx.y;

    // --- stage edges [f][0..47] (96 float4) ---
    if (tid < FT * BB / 4) {
        const float4* E4 = (const float4*)(Edg + (size_t)f0 * BB);
        float4 v = E4[tid];
        int f = tid / 12, j4 = tid % 12;
        *(float4*)&sE[f * ESTR + j4 * 4] = v;
    }
    // --- stage (r, -e*r) pairs ---
    for (int idx = tid; idx < FT * BB; idx += 256) {
        int f = idx / BB, j = idx - f * BB;
        float e = Edg[(size_t)f0 * BB + idx];
        float w = Wid[(size_t)f0 * BB + idx];
        float r = 1.0f / w;
        sRA[f * RASTR + 2 * j]     = r;
        sRA[f * RASTR + 2 * j + 1] = -e * r;
    }
    // --- stage W tile into sC at [f][b+1][d] (768 float4, 3 per thread) ---
    {
        const float4* Wt4 = (const float4*)(W + (size_t)f0 * BB * DD);
        #pragma unroll
        for (int q = 0; q < 3; ++q) {
            int idx4 = tid + q * 256;
            float4 v = Wt4[idx4];
            int idx = idx4 * 4;
            int f   = idx / (BB * DD);
            int rem = idx - f * (BB * DD);
            *(float4*)&sC[f * CSTR + DD + rem] = v;
        }
    }

    // --- issue first pass's x loads before the barrier (hide cold-HBM lat) ---
    const int f_l = tid & 7;
    const int n_l = tid >> 3;                 // 0..31
    const float* xp = X + (f0 + f_l);
    float* op = Out + (size_t)(f0 + f_l) * DD;

    int p = ns;
    float xa = xp[(size_t)(p * 64 + n_l) * FF];
    float xb = xp[(size_t)(p * 64 + n_l + 32) * FF];

    __syncthreads();

    // --- coarse search level -> registers (sE ready; overlaps with scan) ---
    const float* eF  = &sE [f_l * ESTR];
    const float* raF = &sRA[f_l * RASTR];
    const float* cF  = &sC [f_l * CSTR];
    float c4[11];
    #pragma unroll
    for (int m = 0; m < 11; ++m) c4[m] = eF[4 * (m + 1)];

    // --- prefix scan: C[f][j][d] = bias + sum_{b<j} W[f][b][d] (reg-chunked) ---
    if (tid < FT * DD) {
        int f = tid >> 3, d = tid & 7;
        float* c = &sC[f * CSTR + d];
        float acc = Bias[(size_t)(f0 + f) * DD + d];
        c[0] = acc;
        #pragma unroll
        for (int ch = 0; ch < 3; ++ch) {
            float w[16];
            #pragma unroll
            for (int j = 0; j < 16; ++j) w[j] = c[(ch * 16 + j + 1) * DD];
            #pragma unroll
            for (int j = 0; j < 16; ++j) { acc += w[j]; c[(ch * 16 + j + 1) * DD] = acc; }
        }
    }
    __syncthreads();

    // --- main loop: pass p = ns + 48*i covers rows [p*64, p*64+64), 2 rows/thread ---
    #pragma unroll
    for (int i = 0; i < 6; ++i) {
        if (p >= NPASS) break;
        int na = p * 64 + n_l;
        int nb = na + 32;
        float xA = xa, xB = xb;
        int pn = p + NSPLIT;
        if (pn < NPASS) {   // prefetch next pass's x pair
            xa = xp[(size_t)(pn * 64 + n_l) * FF];
            xb = xp[(size_t)(pn * 64 + n_l + 32) * FF];
        }

        // coarse: group g = #{m: x >= E[4m+4]}, k4 = 4g (pure VALU, registers)
        int ga = 0, gb = 0;
        #pragma unroll
        for (int m = 0; m < 11; ++m) {
            ga += (xA >= c4[m]) ? 1 : 0;
            gb += (xB >= c4[m]) ? 1 : 0;
        }
        int k4a = ga * 4, k4b = gb * 4;

        // fine: one aligned b128 of E[k4..k4+3], count 3
        float4 ea = *(const float4*)(eF + k4a);
        float4 eb = *(const float4*)(eF + k4b);
        int ka = k4a + (xA >= ea.y) + (xA >= ea.z) + (xA >= ea.w);
        int kb = k4b + (xB >= eb.y) + (xB >= eb.z) + (xB >= eb.w);

        // gather round: (r,-e*r) b64 + C[k],C[k+1] 4x b128 (one latency round)
        float2 raA = *(const float2*)(raF + 2 * ka);
        float2 raB = *(const float2*)(raF + 2 * kb);
        const float* cKa = cF + ka * DD;
        const float* cKb = cF + kb * DD;
        float4 la0 = *(const float4*)(cKa);
        float4 la1 = *(const float4*)(cKa + 4);
        float4 ha0 = *(const float4*)(cKa + 8);
        float4 ha1 = *(const float4*)(cKa + 12);
        float4 lb0 = *(const float4*)(cKb);
        float4 lb1 = *(const float4*)(cKb + 4);
        float4 hb0 = *(const float4*)(cKb + 8);
        float4 hb1 = *(const float4*)(cKb + 12);

        float ta = fmaf(xA, raA.x, raA.y);
        float tb = fmaf(xB, raB.x, raB.y);

        float4 oa0, oa1, ob0, ob1;
        oa0.x = fmaf(ta, ha0.x - la0.x, la0.x);
        oa0.y = fmaf(ta, ha0.y - la0.y, la0.y);
        oa0.z = fmaf(ta, ha0.z - la0.z, la0.z);
        oa0.w = fmaf(ta, ha0.w - la0.w, la0.w);
        oa1.x = fmaf(ta, ha1.x - la1.x, la1.x);
        oa1.y = fmaf(ta, ha1.y - la1.y, la1.y);
        oa1.z = fmaf(ta, ha1.z - la1.z, la1.z);
        oa1.w = fmaf(ta, ha1.w - la1.w, la1.w);
        ob0.x = fmaf(tb, hb0.x - lb0.x, lb0.x);
        ob0.y = fmaf(tb, hb0.y - lb0.y, lb0.y);
        ob0.z = fmaf(tb, hb0.z - lb0.z, lb0.z);
        ob0.w = fmaf(tb, hb0.w - lb0.w, lb0.w);
        ob1.x = fmaf(tb, hb1.x - lb1.x, lb1.x);
        ob1.y = fmaf(tb, hb1.y - lb1.y, lb1.y);
        ob1.z = fmaf(tb, hb1.z - lb1.z, lb1.z);
        ob1.w = fmaf(tb, hb1.w - lb1.w, lb1.w);

        float4* oA = (float4*)(op + (size_t)na * (FF * DD));
        float4* oB = (float4*)(op + (size_t)nb * (FF * DD));
        oA[0] = oa0; oA[1] = oa1;
        oB[0] = ob0; oB[1] = ob1;

        p = pn;
    }
}

extern "C" void kernel_launch(void* const* d_in, const int* in_sizes, int n_in,
                              void* d_out, int out_size, void* d_ws, size_t ws_size,
                              hipStream_t stream) {
    const float* x     = (const float*)d_in[0];
    const float* edges = (const float*)d_in[1];
    const float* width = (const float*)d_in[2];
    const float* W     = (const float*)d_in[3];
    const float* b     = (const float*)d_in[4];
    float* out = (float*)d_out;

    dim3 grid(FF / FT, NSPLIT);
    cple_kernel<<<grid, 256, 0, stream>>>(x, edges, width, W, b, out);
}

// Round 3
// 166.291 us; speedup vs baseline: 1.0442x; 1.0171x over previous
//
#include <hip/hip_runtime.h>

// CompactPiecewiseLinearEmbeddings: out[n,f,:] = C[f][k] + t*(C[f][k+1]-C[f][k])
// where k = #{j in [1,47] : edges[f][j] <= x[n,f]}, t = (x - edges[f][k]) / width[f][k],
// C[f][j] = bias[f] + sum_{b<j} W[f][b][:]   (sorted boundaries => h = [1..1, t, 0..0])
//
// R7: dense-store remap. R5/R6 occupancy fixes were null => not occupancy-bound.
// No pipe is busy (VALU ~6%, LDS ~25%, HBM ~30%) yet kernel ~3x its traffic
// roofline. Remaining structural defect: store instructions were SPARSE --
// thread (f,n) wrote 2 float4s at +0/+16 within its 32B slot, so each store
// instr wrote 16B chunks at stride 32B (half-density, partial 64B lines =>
// 2x transactions + likely L2 read-for-ownership on the 134MB output, the
// dominant traffic term; the harness fill writes dense lines at 6.6 TB/s).
// Fix: lane h = tid&1 owns d in [4h,4h+4) of each (n,f) task; a wave store
// now covers 4 x 256B fully-dense segments (all full lines). k-search is
// computed redundantly by both half-lanes (VALU is idle). Register pressure
// drops (4 gather float4s vs 8). Keep proven 2048-block grid @ (256,6).

#define NN 16384
#define FF 256
#define BB 48
#define DD 8

#define FT 8               // features per block
#define NSPLIT 64          // n-splits
#define NPB (NN / NSPLIT)  // 256 rows per block

#define ESTR 52            // sE stride: 16B-mult, 20f mod 32 all-distinct over f=0..7
#define RASTR 100          // sRA stride (floats): 8B-mult, 4f mod 32 all-distinct
#define CSTR 396           // sC stride: 16B-mult, 12f mod 32 all-distinct

__global__ __launch_bounds__(256, 6)
void cple_kernel(const float* __restrict__ X,
                 const float* __restrict__ Edg,
                 const float* __restrict__ Wid,
                 const float* __restrict__ W,
                 const float* __restrict__ Bias,
                 float* __restrict__ Out)
{
    __shared__ float sE [FT * ESTR];   // edges [f][j=0..47]
    __shared__ float sRA[FT * RASTR];  // [f][j] -> (r_j, -e_j*r_j) pairs
    __shared__ float sC [FT * CSTR];   // cumulative W + bias, [f][j=0..48][d]

    const int tid = threadIdx.x;
    const int f0  = blockIdx.x * FT;
    const int ns  = blockIdx.y;

    // --- stage edges [f][0..47] (96 float4) ---
    if (tid < FT * BB / 4) {
        const float4* E4 = (const float4*)(Edg + (size_t)f0 * BB);
        float4 v = E4[tid];
        int f = tid / 12, j4 = tid % 12;
        *(float4*)&sE[f * ESTR + j4 * 4] = v;
    }
    // --- stage (r, -e*r) pairs ---
    for (int idx = tid; idx < FT * BB; idx += 256) {
        int f = idx / BB, j = idx - f * BB;
        float e = Edg[(size_t)f0 * BB + idx];
        float w = Wid[(size_t)f0 * BB + idx];
        float r = 1.0f / w;
        sRA[f * RASTR + 2 * j]     = r;
        sRA[f * RASTR + 2 * j + 1] = -e * r;
    }
    // --- stage W tile into sC at [f][b+1][d] (768 float4, 3 per thread) ---
    {
        const float4* Wt4 = (const float4*)(W + (size_t)f0 * BB * DD);
        #pragma unroll
        for (int q = 0; q < 3; ++q) {
            int idx4 = tid + q * 256;
            float4 v = Wt4[idx4];
            int idx = idx4 * 4;
            int f   = idx / (BB * DD);
            int rem = idx - f * (BB * DD);
            *(float4*)&sC[f * CSTR + DD + rem] = v;
        }
    }

    // --- main-loop lane mapping: 16 lanes per n-row (8 f x 2 d-halves) ---
    const int h   = tid & 1;                  // d-half: d in [4h, 4h+4)
    const int f_l = (tid >> 1) & 7;
    const int n_l = tid >> 4;                 // 0..15

    // --- issue first pass's x loads before the barrier (hide cold-HBM lat) ---
    const float* xp = X + (f0 + f_l);
    float* op = Out + (size_t)(f0 + f_l) * DD + h * 4;

    const int nbase = ns * NPB + n_l;
    float xa = xp[(size_t)nbase * FF];
    float xb = xp[(size_t)(nbase + 128) * FF];

    __syncthreads();

    // --- coarse search level -> registers (sE ready; overlaps with scan) ---
    const float* eF  = &sE [f_l * ESTR];
    const float* raF = &sRA[f_l * RASTR];
    const float* cF  = &sC [f_l * CSTR];
    float c4[11];
    #pragma unroll
    for (int m = 0; m < 11; ++m) c4[m] = eF[4 * (m + 1)];

    // --- prefix scan: C[f][j][d] = bias + sum_{b<j} W[f][b][d] (reg-chunked) ---
    if (tid < FT * DD) {
        int f = tid >> 3, d = tid & 7;
        float* c = &sC[f * CSTR + d];
        float acc = Bias[(size_t)(f0 + f) * DD + d];
        c[0] = acc;
        #pragma unroll
        for (int ch = 0; ch < 3; ++ch) {
            float w[16];
            #pragma unroll
            for (int j = 0; j < 16; ++j) w[j] = c[(ch * 16 + j + 1) * DD];
            #pragma unroll
            for (int j = 0; j < 16; ++j) { acc += w[j]; c[(ch * 16 + j + 1) * DD] = acc; }
        }
    }
    __syncthreads();

    // --- main loop: 16 n-rows x 2 groups per iter, 8 iters, 1 float4/task ---
    #pragma unroll
    for (int i = 0; i < 8; ++i) {
        int na = nbase + i * 16;
        int nb = na + 128;
        float xA = xa, xB = xb;
        if (i < 7) {   // prefetch next pair (hides HBM-cold x latency)
            xa = xp[(size_t)(na + 16) * FF];
            xb = xp[(size_t)(nb + 16) * FF];
        }

        // coarse: group g = #{m: x >= E[4m+4]}, k4 = 4g (pure VALU, registers)
        int ga = 0, gb = 0;
        #pragma unroll
        for (int m = 0; m < 11; ++m) {
            ga += (xA >= c4[m]) ? 1 : 0;
            gb += (xB >= c4[m]) ? 1 : 0;
        }
        int k4a = ga * 4, k4b = gb * 4;

        // fine: one aligned b128 of E[k4..k4+3], count 3
        float4 ea = *(const float4*)(eF + k4a);
        float4 eb = *(const float4*)(eF + k4b);
        int ka = k4a + (xA >= ea.y) + (xA >= ea.z) + (xA >= ea.w);
        int kb = k4b + (xB >= eb.y) + (xB >= eb.z) + (xB >= eb.w);

        // gather round: (r,-e*r) b64 + C[k],C[k+1] halves, 2x b128 per task
        float2 raA = *(const float2*)(raF + 2 * ka);
        float2 raB = *(const float2*)(raF + 2 * kb);
        const float* cKa = cF + ka * DD + h * 4;
        const float* cKb = cF + kb * DD + h * 4;
        float4 la = *(const float4*)(cKa);
        float4 ha = *(const float4*)(cKa + DD);
        float4 lb = *(const float4*)(cKb);
        float4 hb = *(const float4*)(cKb + DD);

        float ta = fmaf(xA, raA.x, raA.y);
        float tb = fmaf(xB, raB.x, raB.y);

        float4 oa, ob;
        oa.x = fmaf(ta, ha.x - la.x, la.x);
        oa.y = fmaf(ta, ha.y - la.y, la.y);
        oa.z = fmaf(ta, ha.z - la.z, la.z);
        oa.w = fmaf(ta, ha.w - la.w, la.w);
        ob.x = fmaf(tb, hb.x - lb.x, lb.x);
        ob.y = fmaf(tb, hb.y - lb.y, lb.y);
        ob.z = fmaf(tb, hb.z - lb.z, lb.z);
        ob.w = fmaf(tb, hb.w - lb.w, lb.w);

        // dense stores: lanes (f_l,h) cover 256B contiguous per n-row
        *(float4*)(op + (size_t)na * (FF * DD)) = oa;
        *(float4*)(op + (size_t)nb * (FF * DD)) = ob;
    }
}

extern "C" void kernel_launch(void* const* d_in, const int* in_sizes, int n_in,
                              void* d_out, int out_size, void* d_ws, size_t ws_size,
                              hipStream_t stream) {
    const float* x     = (const float*)d_in[0];
    const float* edges = (const float*)d_in[1];
    const float* width = (const float*)d_in[2];
    const float* W     = (const float*)d_in[3];
    const float* b     = (const float*)d_in[4];
    float* out = (float*)d_out;

    dim3 grid(FF / FT, NSPLIT);
    cple_kernel<<<grid, 256, 0, stream>>>(x, edges, width, W, b, out);
}

// Round 4
// 161.122 us; speedup vs baseline: 1.0777x; 1.0321x over previous
//
#include <hip/hip_runtime.h>

// CompactPiecewiseLinearEmbeddings: out[n,f,:] = C[f][k] + t*(C[f][k+1]-C[f][k])
// where k = #{j in [1,47] : edges[f][j] <= x[n,f]}, t = (x - edges[f][k]) / width[f][k],
// C[f][j] = bias[f] + sum_{b<j} W[f][b][:]   (sorted boundaries => h = [1..1, t, 0..0])
//
// R8: DRAM burst-width attack. R5/R6 (occupancy) and R7 (line density) were
// all null => the shared defect of every FT=8 variant is burst geometry:
// each wave-store scattered 16 lines at 8KB stride (256B bursts), and each
// 8KB output row was assembled by 32 blocks on different XCDs. Scattered
// 256B bursts run at ~half DRAM efficiency -- magnitude matches the ~78us
// kernel vs ~24us traffic roofline. Fix: FT=32 + 1024-thread block, lane map
// (h=tid&1, f=(tid>>1)&31, wave=tid>>6) => ALL 64 lanes of a wave write ONE
// output row: every store instr is 1024B contiguous (16 consecutive lines),
// like the 6.6TB/s harness fill. x loads become dense 128B spans too.
// LDS 68.5KB => exactly 2 blocks/CU (137KB), grid 8x64=512 = 2/CU, 32 w/CU.
// Random-k C-gather conflict structure unchanged (32 random granules/wave).

#define NN 16384
#define FF 256
#define BB 48
#define DD 8

#define FT 32              // features per block
#define NT 1024            // threads per block
#define NSPLIT 64          // n-splits
#define NPB (NN / NSPLIT)  // 256 rows per block
#define RPI 16             // rows per iter (NT/64)
#define ITERS (NPB / RPI)  // 16

#define ESTR 52            // sE stride: 16B-mult, granule 13f mod 8 distinct
#define RASTR 100          // sRA stride (floats)
#define CSTR 396           // sC stride: 16B-mult, granule 99f mod 8 distinct

__global__ __launch_bounds__(NT, 8)
void cple_kernel(const float* __restrict__ X,
                 const float* __restrict__ Edg,
                 const float* __restrict__ Wid,
                 const float* __restrict__ W,
                 const float* __restrict__ Bias,
                 float* __restrict__ Out)
{
    __shared__ float sE [FT * ESTR];   // edges [f][j=0..47]        (6.5 KB)
    __shared__ float sRA[FT * RASTR];  // [f][j] -> (r, -e*r) pairs (12.5 KB)
    __shared__ float sC [FT * CSTR];   // cum W + bias [f][j][d]    (49.5 KB)

    const int tid = threadIdx.x;
    const int f0  = blockIdx.x * FT;
    const int ns  = blockIdx.y;

    // --- stage edges [f][0..47] (384 float4) ---
    if (tid < FT * BB / 4) {
        const float4* E4 = (const float4*)(Edg + (size_t)f0 * BB);
        float4 v = E4[tid];
        int f = tid / 12, j4 = tid % 12;
        *(float4*)&sE[f * ESTR + j4 * 4] = v;
    }
    // --- stage (r, -e*r) pairs (1536 elems) ---
    for (int idx = tid; idx < FT * BB; idx += NT) {
        int f = idx / BB, j = idx - f * BB;
        float e = Edg[(size_t)f0 * BB + idx];
        float w = Wid[(size_t)f0 * BB + idx];
        float r = 1.0f / w;
        sRA[f * RASTR + 2 * j]     = r;
        sRA[f * RASTR + 2 * j + 1] = -e * r;
    }
    // --- stage W tile into sC at [f][b+1][d] (3072 float4, 3 per thread) ---
    {
        const float4* Wt4 = (const float4*)(W + (size_t)f0 * BB * DD);
        #pragma unroll
        for (int q = 0; q < 3; ++q) {
            int idx4 = tid + q * NT;
            float4 v = Wt4[idx4];
            int idx = idx4 * 4;
            int f   = idx / (BB * DD);
            int rem = idx - f * (BB * DD);
            *(float4*)&sC[f * CSTR + DD + rem] = v;
        }
    }

    // --- main-loop lane mapping: whole wave on ONE n-row ---
    const int h   = tid & 1;                  // d-half: d in [4h, 4h+4)
    const int f_l = (tid >> 1) & 31;          // feature within tile
    const int w_l = tid >> 6;                 // wave id = row within slab (0..15)

    // --- issue first x load before the barrier (hide cold-HBM latency) ---
    const float* xp = X + (f0 + f_l);
    float* op = Out + (size_t)(f0 + f_l) * DD + h * 4;

    const int nbase = ns * NPB + w_l;
    float xn = xp[(size_t)nbase * FF];

    __syncthreads();

    // --- coarse search level -> registers ---
    const float* eF  = &sE [f_l * ESTR];
    const float* raF = &sRA[f_l * RASTR];
    const float* cF  = &sC [f_l * CSTR] + h * 4;
    float c4[11];
    #pragma unroll
    for (int m = 0; m < 11; ++m) c4[m] = eF[4 * (m + 1)];

    // --- prefix scan: C[f][j][d] = bias + sum_{b<j} W[f][b][d] (reg-chunked) ---
    if (tid < FT * DD) {
        int f = tid >> 3, d = tid & 7;
        float* c = &sC[f * CSTR + d];
        float acc = Bias[(size_t)(f0 + f) * DD + d];
        c[0] = acc;
        #pragma unroll
        for (int ch = 0; ch < 3; ++ch) {
            float w[16];
            #pragma unroll
            for (int j = 0; j < 16; ++j) w[j] = c[(ch * 16 + j + 1) * DD];
            #pragma unroll
            for (int j = 0; j < 16; ++j) { acc += w[j]; c[(ch * 16 + j + 1) * DD] = acc; }
        }
    }
    __syncthreads();

    // --- main loop: 16 rows/iter (1 row per wave), 16 iters ---
    #pragma unroll
    for (int i = 0; i < ITERS; ++i) {
        int n = nbase + i * RPI;
        float xc = xn;
        if (i < ITERS - 1)   // prefetch next row's x (dense 128B span per wave)
            xn = xp[(size_t)(n + RPI) * FF];

        // coarse: group g = #{m: x >= E[4m+4]}, k4 = 4g (pure VALU, registers)
        int g = 0;
        #pragma unroll
        for (int m = 0; m < 11; ++m) g += (xc >= c4[m]) ? 1 : 0;
        int k4 = g * 4;

        // fine: one aligned b128 of E[k4..k4+3], count 3
        float4 e = *(const float4*)(eF + k4);
        int k = k4 + (xc >= e.y) + (xc >= e.z) + (xc >= e.w);

        // gather: (r,-e*r) b64 + C[k],C[k+1] half-d, 2x b128 per lane
        float2 ra = *(const float2*)(raF + 2 * k);
        const float* cK = cF + k * DD;
        float4 lo = *(const float4*)(cK);
        float4 hi = *(const float4*)(cK + DD);

        float t = fmaf(xc, ra.x, ra.y);

        float4 o;
        o.x = fmaf(t, hi.x - lo.x, lo.x);
        o.y = fmaf(t, hi.y - lo.y, lo.y);
        o.z = fmaf(t, hi.z - lo.z, lo.z);
        o.w = fmaf(t, hi.w - lo.w, lo.w);

        // dense store: wave covers 1024B contiguous of row n
        *(float4*)(op + (size_t)n * (FF * DD)) = o;
    }
}

extern "C" void kernel_launch(void* const* d_in, const int* in_sizes, int n_in,
                              void* d_out, int out_size, void* d_ws, size_t ws_size,
                              hipStream_t stream) {
    const float* x     = (const float*)d_in[0];
    const float* edges = (const float*)d_in[1];
    const float* width = (const float*)d_in[2];
    const float* W     = (const float*)d_in[3];
    const float* b     = (const float*)d_in[4];
    float* out = (float*)d_out;

    dim3 grid(FF / FT, NSPLIT);
    cple_kernel<<<grid, NT, 0, stream>>>(x, edges, width, W, b, out);
}